// Round 3
// baseline (87.374 us; speedup 1.0000x reference)
//
#include <hip/hip_runtime.h>

#define B_ 8
#define H_ 96
#define W_ 96
#define O_ 8
#define HW_ (H_ * W_)          // 9216
#define NT 512                 // threads per block (8 waves)
#define NCH 72                 // HW chunks -> phase-1 grid = (NCH, B_) = 576 blocks
#define PPB (HW_ / NCH)        // 128 pixels per block
#define ITERS (PPB / 64)       // 2 compute iterations (64 pixels x 8 o per iter)

// Phase 1: block = (b, pixel-chunk), all 8 o's. Thread t: o = t&7, pg = t>>3.
// Fully coalesced loads (obj 12 B/lane, wp 16 B/lane contiguous).
// Accumulates 60 structured sums per (pixel,o):
//   MtM = sum_px (sum_r x_r x_r^T) (x) (q q^T); 6 unique X * 10 unique Q.
// Writes per-block 8x60 partials to ws — no atomics, no output pre-zeroing.
__global__ __launch_bounds__(NT) void mtm_partial(
    const float* __restrict__ obj,   // (B,H,W,O,3)
    const float* __restrict__ wpx,   // (B,H,W,O,4)
    const float* __restrict__ cam,   // (B,3,3)
    const float* __restrict__ ck,    // (B,2,2)
    float* __restrict__ ws)          // (B, NCH, 8, 60) partials
{
    const int chunk = blockIdx.x;
    const int b     = blockIdx.y;

    const float* cm = cam + b * 9;
    const float* k4 = ck  + b * 4;
    const float a   = -cm[0];
    const float c   = -cm[4];
    const float k00 = k4[0];
    const float k01 = k4[1];
    const float Bu  = k4[2] - cm[2];
    const float Bv  = k4[3] - cm[5];

    const int o  = threadIdx.x & 7;
    const int pg = threadIdx.x >> 3;          // 0..63

    float acc[60];
#pragma unroll
    for (int s = 0; s < 60; ++s) acc[s] = 0.f;

#pragma unroll
    for (int it = 0; it < ITERS; ++it) {
        const int p = chunk * PPB + it * 64 + pg;
        const int h = p / W_;
        const int w = p - h * W_;
        const int slot = (b * HW_ + p) * O_ + o;

        const float* ob = obj + (size_t)slot * 3;
        const float p1 = ob[0], p2 = ob[1], p3 = ob[2];
        const float4 wp = *(const float4*)(wpx + (size_t)slot * 4);

        const float du = fmaf((float)w, k00, Bu);
        const float dv = fmaf((float)h, k01, Bv);

        const float x00 = wp.x * a;
        const float x01 = wp.y * c;
        const float x02 = fmaf(wp.x, du, wp.y * dv);
        const float x10 = wp.z * a;
        const float x11 = wp.w * c;
        const float x12 = fmaf(wp.z, du, wp.w * dv);

        float Xa[6];
        Xa[0] = fmaf(x00, x00, x10 * x10);
        Xa[1] = fmaf(x00, x01, x10 * x11);
        Xa[2] = fmaf(x00, x02, x10 * x12);
        Xa[3] = fmaf(x01, x01, x11 * x11);
        Xa[4] = fmaf(x01, x02, x11 * x12);
        Xa[5] = fmaf(x02, x02, x12 * x12);

        float Q[10];
        Q[0] = p1 * p1; Q[1] = p1 * p2; Q[2] = p1 * p3; Q[3] = p1;
        Q[4] = p2 * p2; Q[5] = p2 * p3; Q[6] = p2;
        Q[7] = p3 * p3; Q[8] = p3;
        Q[9] = 1.f;

#pragma unroll
        for (int ij = 0; ij < 6; ++ij) {
#pragma unroll
            for (int kl = 0; kl < 10; ++kl)
                acc[ij * 10 + kl] = fmaf(Xa[ij], Q[kl], acc[ij * 10 + kl]);
        }
    }

    // In-wave reduce over pixel-groups (lane bits 3,4,5).
#pragma unroll
    for (int s = 0; s < 60; ++s) {
        float v = acc[s];
        v += __shfl_xor(v, 8,  64);
        v += __shfl_xor(v, 16, 64);
        v += __shfl_xor(v, 32, 64);
        acc[s] = v;
    }

    __shared__ float lds[64 * 60];   // (wave*8+o) x 60
    const int lane = threadIdx.x & 63;
    const int wave = threadIdx.x >> 6;
    if (lane < 8) {
#pragma unroll
        for (int s = 0; s < 60; ++s)
            lds[(wave * 8 + lane) * 60 + s] = acc[s];
    }
    __syncthreads();

    // Block-level fold over 8 waves; coalesced 480-float store of partials.
    if (threadIdx.x < 480) {
        const int oo = threadIdx.x / 60;
        const int ss = threadIdx.x - oo * 60;
        float v = 0.f;
#pragma unroll
        for (int w = 0; w < 8; ++w) v += lds[(w * 8 + oo) * 60 + ss];
        ws[((size_t)b * NCH + chunk) * 480 + threadIdx.x] = v;
    }
}

// Phase 2: one block per (b,o); fold NCH chunk-partials, scatter 169 outputs
// (row/col 9 structurally zero — written as 0, so no d_out pre-zeroing).
__global__ __launch_bounds__(256) void mtm_reduce(
    const float* __restrict__ ws,    // (B, NCH, 8, 60)
    float* __restrict__ out)         // (B,O,13,13)
{
    const int bo = blockIdx.x;       // b*8+o
    const int b  = bo >> 3;
    const int o  = bo & 7;
    const int t  = threadIdx.x;

    __shared__ float S4[60][4];
    __shared__ float S[60];

    if (t < 240) {
        const int s = t >> 2, part = t & 3;
        float v = 0.f;
#pragma unroll
        for (int ch = part; ch < NCH; ch += 4)
            v += ws[((size_t)b * NCH + ch) * 480 + o * 60 + s];
        S4[s][part] = v;
    }
    __syncthreads();
    if (t < 60) S[t] = S4[t][0] + S4[t][1] + S4[t][2] + S4[t][3];
    __syncthreads();

    if (t < 169) {
        const int r  = t / 13;
        const int cc = t - r * 13;
        float val = 0.f;
        if (r != 9 && cc != 9) {
            int i, k, j, l;
            if (r < 9)  { i = r / 3;  k = r - i * 3; } else { i = r - 10;  k = 3; }
            if (cc < 9) { j = cc / 3; l = cc - j * 3; } else { j = cc - 10; l = 3; }
            const int ii = i < j ? i : j, jj = i < j ? j : i;
            const int kk = k < l ? k : l, ll = k < l ? l : k;
            const int ijIdx = ii * (5 - ii) / 2 + jj;   // 0..5
            const int klIdx = kk * (7 - kk) / 2 + ll;   // 0..9
            val = S[ijIdx * 10 + klIdx];
        }
        out[(size_t)bo * 169 + t] = val;
    }
}

extern "C" void kernel_launch(void* const* d_in, const int* in_sizes, int n_in,
                              void* d_out, int out_size, void* d_ws, size_t ws_size,
                              hipStream_t stream) {
    const float* obj = (const float*)d_in[0];
    const float* wpx = (const float*)d_in[1];
    const float* cam = (const float*)d_in[2];
    const float* ck  = (const float*)d_in[3];
    float* ws  = (float*)d_ws;
    float* out = (float*)d_out;

    mtm_partial<<<dim3(NCH, B_), dim3(NT), 0, stream>>>(obj, wpx, cam, ck, ws);
    mtm_reduce<<<dim3(B_ * O_), dim3(256), 0, stream>>>(ws, out);
}